// Round 1
// baseline (1614.518 us; speedup 1.0000x reference)
//
#include <hip/hip_runtime.h>
#include <math.h>

#define Hh 64
#define Bb 16
#define Tt 64
#define Kk 32

// ws layout (floats):
//   pe:     [65][64]        offset 0        (4160)
//   et:     [64][16][64]    offset 4160     (65536)
//   energy: [64][16][32]    offset 69696    (32768)

__device__ __forceinline__ float gelu_exact(float x) {
    return 0.5f * x * (1.0f + erff(x * 0.7071067811865476f));
}

__global__ void pe_kernel(float* __restrict__ pe) {
    int p = blockIdx.x;   // 0..64
    int h = threadIdx.x;  // 0..63
    int i = h >> 1;
    double div = pow(10000.0, (double)(2 * i) / 64.0);
    double ang = (double)p * div;
    double v = (h & 1) ? cos(ang) : sin(ang);
    pe[p * 64 + h] = (float)v;
}

// Phase 1: sequential chains, one block per batch b.
// Thread layout: cg = tid%16 (4 cols), rg = tid/16 (row within 16-row group).
__global__ __launch_bounds__(256) void phase1_kernel(
    const int* __restrict__ nb_ids, const int* __restrict__ pidx,
    const float* __restrict__ weights, const float* __restrict__ biases,
    const float* __restrict__ node_bias, const float* __restrict__ positions,
    const float* __restrict__ pe, float* __restrict__ et_g,
    float* __restrict__ energy)
{
    int b = blockIdx.x;
    int tid = threadIdx.x;
    int cg = tid & 15;
    int rg = tid >> 4;

    __shared__ float et_s[64];
    __shared__ float part[16][64];
    __shared__ float pos_s[64];
    __shared__ float m_s;

    if (tid < 64) pos_s[tid] = positions[tid];
    __syncthreads();
    if (tid == 0) {
        float m = -1e30f;
        for (int j = 0; j < 64; ++j) m = fmaxf(m, pos_s[j]);
        m_s = m;
    }
    if (tid < 64) {
        int nid = nb_ids[b * (Tt * Kk * 2)];  // neighbor_ids[b,0,0,0]
        float e0 = gelu_exact(0.015625f + node_bias[(long long)nid * 64 + tid] + pe[tid]);
        et_s[tid] = e0;
        et_g[(long long)b * 64 + tid] = e0;  // et for t=0
    }
    __syncthreads();
    float m = m_s;

    float snum = 0.f;  // thread d = tid (<64) running softmax numerator
    float sden = 0.f;

    const int* pb = pidx + (long long)b * Tt * Kk;

    // preload W for t=0 into registers
    float4 c0, c1, c2, c3, n0, n1, n2, n3;
    {
        const float4* wp = (const float4*)(weights + (long long)pb[0] * 4096);
        c0 = wp[(0 * 16 + rg) * 16 + cg];
        c1 = wp[(1 * 16 + rg) * 16 + cg];
        c2 = wp[(2 * 16 + rg) * 16 + cg];
        c3 = wp[(3 * 16 + rg) * 16 + cg];
    }
    n0 = c0; n1 = c1; n2 = c2; n3 = c3;

    for (int t = 0; t < 64; ++t) {
        if (t < 63) {  // prefetch next step's weights (indices known ahead)
            const float4* wp = (const float4*)(weights + (long long)pb[(t + 1) * Kk] * 4096);
            n0 = wp[(0 * 16 + rg) * 16 + cg];
            n1 = wp[(1 * 16 + rg) * 16 + cg];
            n2 = wp[(2 * 16 + rg) * 16 + cg];
            n3 = wp[(3 * 16 + rg) * 16 + cg];
        }
        // partial gemv: rows {rg, 16+rg, 32+rg, 48+rg}, cols 4cg..4cg+3
        float4 a; a.x = a.y = a.z = a.w = 0.f;
        float e;
        e = et_s[0 * 16 + rg]; a.x += e * c0.x; a.y += e * c0.y; a.z += e * c0.z; a.w += e * c0.w;
        e = et_s[1 * 16 + rg]; a.x += e * c1.x; a.y += e * c1.y; a.z += e * c1.z; a.w += e * c1.w;
        e = et_s[2 * 16 + rg]; a.x += e * c2.x; a.y += e * c2.y; a.z += e * c2.z; a.w += e * c2.w;
        e = et_s[3 * 16 + rg]; a.x += e * c3.x; a.y += e * c3.y; a.z += e * c3.z; a.w += e * c3.w;
        *(float4*)&part[rg][4 * cg] = a;
        __syncthreads();

        if (tid < 64) {
            float s = 0.f;
            #pragma unroll
            for (int r = 0; r < 16; ++r) s += part[r][tid];
            long long idx0 = (long long)pb[t * Kk];
            float x = s + biases[idx0 * 64 + tid] + pe[(t + 1) * 64 + tid];
            float cval = gelu_exact(x);
            float sq = cval * cval;
            #pragma unroll
            for (int off = 32; off > 0; off >>= 1) sq += __shfl_down(sq, off);
            if (tid == 0) energy[(long long)t * Bb * Kk + b * Kk + 0] = sqrtf(sq);
            float wexp = expf(pos_s[t] - m);
            snum += cval * wexp;
            sden += wexp;
            float etn = snum / sden;
            et_s[tid] = etn;
            if (t < 63) et_g[(long long)(t + 1) * Bb * 64 + b * 64 + tid] = etn;
        }
        __syncthreads();
        c0 = n0; c1 = n1; c2 = n2; c3 = n3;
    }
}

// Phase 2: all (t,b,k>=1) energies; one block per (t,b), one wave per k strided by 4.
__global__ __launch_bounds__(256) void phase2_kernel(
    const int* __restrict__ pidx, const float* __restrict__ weights,
    const float* __restrict__ biases, const float* __restrict__ pe,
    const float* __restrict__ et_g, float* __restrict__ energy)
{
    int blk = blockIdx.x;
    int t = blk & 63;
    int b = blk >> 6;
    int tid = threadIdx.x;
    int wave = tid >> 6;
    int lane = tid & 63;
    int cg = lane & 15;   // column group: cols 4cg..4cg+3
    int rq = lane >> 4;   // row quadrant: rows 4j+rq

    __shared__ float et_s[64];
    __shared__ float pe_s[64];
    if (tid < 64) {
        et_s[tid] = et_g[(long long)t * Bb * 64 + b * 64 + tid];
        pe_s[tid] = pe[(t + 1) * 64 + tid];
    }
    __syncthreads();

    const int* pbt = pidx + (long long)b * Tt * Kk + t * Kk;

    for (int k = 1 + wave; k < 32; k += 4) {
        long long eidx = (long long)pbt[k];
        const float4* wp = (const float4*)(weights + eidx * 4096);
        float4 a; a.x = a.y = a.z = a.w = 0.f;
        #pragma unroll
        for (int j = 0; j < 16; ++j) {
            int h = 4 * j + rq;
            float4 w4 = wp[h * 16 + cg];  // one dwordx4/lane -> 4 full rows/wave, 1KB contiguous
            float e = et_s[h];
            a.x += e * w4.x; a.y += e * w4.y; a.z += e * w4.z; a.w += e * w4.w;
        }
        // reduce over row quadrants (lanes differing in bits 4,5)
        a.x += __shfl_xor(a.x, 16); a.y += __shfl_xor(a.y, 16);
        a.z += __shfl_xor(a.z, 16); a.w += __shfl_xor(a.w, 16);
        a.x += __shfl_xor(a.x, 32); a.y += __shfl_xor(a.y, 32);
        a.z += __shfl_xor(a.z, 32); a.w += __shfl_xor(a.w, 32);

        float4 b4 = *(const float4*)(biases + eidx * 64 + 4 * cg);
        float4 p4 = *(const float4*)&pe_s[4 * cg];
        float g0 = gelu_exact(a.x + b4.x + p4.x);
        float g1 = gelu_exact(a.y + b4.y + p4.y);
        float g2 = gelu_exact(a.z + b4.z + p4.z);
        float g3 = gelu_exact(a.w + b4.w + p4.w);
        float local = g0 * g0 + g1 * g1 + g2 * g2 + g3 * g3;
        // sum over the 16 column groups (bits 0..3); bits 4,5 are duplicates
        #pragma unroll
        for (int off = 1; off < 16; off <<= 1) local += __shfl_xor(local, off);
        if (lane == 0) energy[(long long)t * Bb * Kk + b * Kk + k] = sqrtf(local);
    }
}

// Phase 3: loss = sum_{t,b} (logsumexp_k(energy) - energy[k=0]) / (T*B)
__global__ __launch_bounds__(1024) void phase3_kernel(
    const float* __restrict__ energy, float* __restrict__ out)
{
    int tid = threadIdx.x;  // (t,b) pair: t = tid/16, b = tid%16 -> energy + 32*tid
    const float* e = energy + (long long)tid * 32;
    float mx = e[0];
    #pragma unroll
    for (int k = 1; k < 32; ++k) mx = fmaxf(mx, e[k]);
    float s = 0.f;
    #pragma unroll
    for (int k = 0; k < 32; ++k) s += expf(e[k] - mx);
    float v = (mx + logf(s)) - e[0];

    __shared__ float red[16];
    #pragma unroll
    for (int off = 32; off > 0; off >>= 1) v += __shfl_down(v, off);
    if ((tid & 63) == 0) red[tid >> 6] = v;
    __syncthreads();
    if (tid < 16) {
        float r = red[tid];
        #pragma unroll
        for (int off = 8; off > 0; off >>= 1) r += __shfl_down(r, off);
        if (tid == 0) out[0] = r / (float)(Bb * Tt);
    }
}

extern "C" void kernel_launch(void* const* d_in, const int* in_sizes, int n_in,
                              void* d_out, int out_size, void* d_ws, size_t ws_size,
                              hipStream_t stream) {
    const int* nb_ids       = (const int*)d_in[0];    // (B,T,K,2)
    const int* pidx         = (const int*)d_in[1];    // (B,T,K)
    const float* weights    = (const float*)d_in[2];  // (E,H,H)
    const float* biases     = (const float*)d_in[3];  // (E,1,H)
    const float* node_bias  = (const float*)d_in[4];  // (N,1,H)
    const float* positions  = (const float*)d_in[5];  // (1,SEQ,1)
    float* out = (float*)d_out;

    float* ws = (float*)d_ws;
    float* pe     = ws;                  // 4160
    float* et     = ws + 4160;           // 65536
    float* energy = ws + 4160 + 65536;   // 32768

    pe_kernel<<<65, 64, 0, stream>>>(pe);
    phase1_kernel<<<16, 256, 0, stream>>>(nb_ids, pidx, weights, biases,
                                          node_bias, positions, pe, et, energy);
    phase2_kernel<<<Tt * Bb, 256, 0, stream>>>(pidx, weights, biases, pe, et, energy);
    phase3_kernel<<<1, 1024, 0, stream>>>(energy, out);
}